// Round 7
// baseline (1187.029 us; speedup 1.0000x reference)
//
#include <hip/hip_runtime.h>
#include <math.h>

#define BB 8
#define CC 256
#define HH 128
#define WW 128
#define NN (HH*WW)          // 16384
#define NBVEC 16
#define CSPLIT 16
#define CCHUNK (CC/CSPLIT)  // 16
#define NBX (NN/256)        // 64  (finish blocks / bmax partials)
#define NBB 16              // fused nb blocks
#define NSUB 4              // sub-tiles per fused block (NBB*NSUB*256 == NN)

// ---------------- workspace layout (bytes) ----------------
// score  double[B][N]           @ 0        : 1048576
// d2part float [CSPLIT][B][N]   @ 1048576  : 8388608
// wpart  double[NBB][B][C]      @ 9437184  : 262144
// sumSim double[2][B]           @ 9699328  : 128
// bmaxv  double[B][NBX]         @ 9699456  : 4096
// bmaxi  int   [B][NBX]         @ 9703552  : 2048
// total ~9.7 MB

// Fused kernel: ONE x-pass per iteration, REGISTER-ONLY main loop.
// Round-6 post-mortem: ~65 ds-ops + 2 barriers per wave per sub-tile
// (~8300 ds-instr/CU/pass ~= 20 us) existed only to transpose x for
// pass B. Eliminated: thread t holds a full 16-channel column in r[16],
// so pass B is wacc[c] += sim_t * r[c] (registers); the cross-thread
// n-sum moves to a once-per-block LDS reduction. Pass A reads r[] and
// uniform-broadcast rvr[] -> main loop has NO LDS and NO barriers.
// d2part chain order/bits identical to rounds 3-6 -> same argmax path.
__global__ __launch_bounds__(256, 8)
void fused_kernel(const float* __restrict__ x,
                  float* __restrict__ out,
                  const double* __restrict__ bmaxv,
                  const int* __restrict__ bmaxi,
                  float* __restrict__ d2part,
                  double* __restrict__ wpart, int iter)
{
    const int b  = blockIdx.z;
    const int cz = blockIdx.y;
    const int nb = blockIdx.x;     // 0..15
    const int t  = threadIdx.x;

    __shared__ union UScratch {
        struct { double val[NBX]; int idx[NBX]; } mx;  // prologue argmax
        float w[CCHUNK][257];                          // epilogue reduce (<=2-way)
    } s_u;
    __shared__ double s_part[16][17];

    float* out_sims   = out + (size_t)NBVEC*BB*CC;            // [NBVEC][B][N]
    float* out_selpos = out_sims + (size_t)NBVEC*BB*NN;       // [B][N]

    // ---- select index (redundant per block; first-occurrence tie-break) ----
    int sel = NN/2;
    if (iter > 0 && iter < NBVEC) {
        if (t < NBX) { s_u.mx.val[t] = bmaxv[b*NBX + t]; s_u.mx.idx[t] = bmaxi[b*NBX + t]; }
        __syncthreads();
        for (int s = NBX/2; s > 0; s >>= 1) {
            if (t < s) {
                double v2 = s_u.mx.val[t+s]; int i2 = s_u.mx.idx[t+s];
                if (v2 > s_u.mx.val[t] || (v2 == s_u.mx.val[t] && i2 < s_u.mx.idx[t])) {
                    s_u.mx.val[t] = v2; s_u.mx.idx[t] = i2;
                }
            }
            __syncthreads();
        }
        sel = s_u.mx.idx[0];   // all threads read here; union not rewritten
    }                          // until after the epilogue barrier

    if (iter < NBVEC && t == 0 && nb == 0 && cz == 0)
        out_selpos[(size_t)b*NN + sel] += 1.0f;

    // ---- rv into registers via uniform-address loads (HW broadcast) ----
    float rvr[CCHUNK];
    if (iter < NBVEC) {
        const float* rvp = x + ((size_t)b*CC + (size_t)cz*CCHUNK)*NN + sel;
        #pragma unroll
        for (int c = 0; c < CCHUNK; ++c)
            rvr[c] = rvp[(size_t)c*NN];
    }

    const float* xb   = x + ((size_t)b*CC + (size_t)cz*CCHUNK)*NN + (size_t)nb*(NSUB*256);
    const float* simb = out_sims + (size_t)(iter-1)*BB*NN + (size_t)b*NN + (size_t)nb*(NSUB*256);

    float wacc[CCHUNK];
    #pragma unroll
    for (int c = 0; c < CCHUNK; ++c) wacc[c] = 0.0f;

    // ---- main loop: register-only, barrier-free ----
    #pragma unroll
    for (int sub = 0; sub < NSUB; ++sub) {
        float r[CCHUNK];
        #pragma unroll
        for (int c = 0; c < CCHUNK; ++c)
            r[c] = xb[(size_t)c*NN + sub*256 + t];
        float simv = 0.0f;
        if (iter > 0) simv = simb[sub*256 + t];

        // pass A: d2 partial (fp64 chain, fixed c-ascending order;
        // bit-identical to rounds 3-6)
        if (iter < NBVEC) {
            double acc = 0.0;
            #pragma unroll
            for (int c = 0; c < CCHUNK; ++c) {
                double diff = (double)r[c] - (double)rvr[c];
                acc = fma(diff, diff, acc);
            }
            d2part[((size_t)cz*BB + b)*NN + (size_t)nb*(NSUB*256) + sub*256 + t] = (float)acc;
        }

        // pass B: per-thread fp32 accumulation (4-term chain; feeds repr
        // only, never the argmax path)
        if (iter > 0) {
            #pragma unroll
            for (int c = 0; c < CCHUNK; ++c)
                wacc[c] = fmaf(simv, r[c], wacc[c]);
        }
    }

    // ---- once-per-block wsum reduction (deterministic fixed order) ----
    if (iter > 0) {
        __syncthreads();                 // prologue reads of s_u complete
        #pragma unroll
        for (int c = 0; c < CCHUNK; ++c)
            s_u.w[c][t] = wacc[c];
        __syncthreads();
        const int c = t & 15;            // 16 c's
        const int g = t >> 4;            // 16 n-groups of 16
        double t0 = 0.0, t1 = 0.0;
        #pragma unroll
        for (int k = 0; k < 16; k += 2) {
            t0 += (double)s_u.w[c][g*16 + k];
            t1 += (double)s_u.w[c][g*16 + k + 1];
        }
        s_part[g][c] = t0 + t1;
        __syncthreads();
        if (t < CCHUNK) {
            double u0 = 0.0, u1 = 0.0, u2 = 0.0, u3 = 0.0;
            #pragma unroll
            for (int gg = 0; gg < 16; gg += 4) {
                u0 += s_part[gg+0][t];
                u1 += s_part[gg+1][t];
                u2 += s_part[gg+2][t];
                u3 += s_part[gg+3][t];
            }
            wpart[((size_t)nb*BB + b)*CC + (size_t)cz*CCHUNK + t] = (u0+u1)+(u2+u3);
        }
    }
}

// Finisher: grid (N/256, B) — as round 4/6; wpart now has NBB=16 rows.
__global__ void finish_kernel(float* __restrict__ out,
                              double* __restrict__ score,
                              const float* __restrict__ d2part,
                              double* __restrict__ sumSim,
                              const double* __restrict__ wpart,
                              double* __restrict__ bmaxv,
                              int* __restrict__ bmaxi, int iter)
{
    const int b = blockIdx.y;
    const int t = threadIdx.x;
    const int n = blockIdx.x * 256 + t;
    const size_t si = (size_t)b*NN + n;
    const int lane = t & 63;
    const int wave = t >> 6;

    double a0 = 0.0, a1 = 0.0;
    #pragma unroll
    for (int cz = 0; cz < CSPLIT; cz += 2) {
        a0 += (double)d2part[((size_t)cz*BB + b)*NN + n];
        a1 += (double)d2part[((size_t)(cz+1)*BB + b)*NN + n];
    }
    double d2 = a0 + a1;

    double d   = sqrt(d2 + 1e-12);
    double sim = exp(-(d / 20.0));

    float* out_sims = out + (size_t)NBVEC*BB*CC;   // [NBVEC][B][N]
    out_sims[(size_t)iter*BB*NN + si] = (float)sim;

    double sc;
    if (iter == 0) sc = 1.0 - sim;
    else           sc = (1.0 - sim) * score[si];
    score[si] = sc;

    // per-wave sumSim reduce (butterfly, fixed order)
    double v = sim;
    #pragma unroll
    for (int off = 32; off > 0; off >>= 1) v += __shfl_down(v, off, 64);

    // per-wave argmax reduce (max, lower-idx-on-tie: semilattice)
    double bv = sc; int bi = n;
    #pragma unroll
    for (int off = 32; off > 0; off >>= 1) {
        double ov = __shfl_down(bv, off, 64);
        int    oi = __shfl_down(bi, off, 64);
        if (ov > bv || (ov == bv && oi < bi)) { bv = ov; bi = oi; }
    }

    __shared__ double s_ws[4];
    __shared__ double s_wv[4];
    __shared__ int    s_wi[4];
    if (lane == 0) { s_ws[wave] = v; s_wv[wave] = bv; s_wi[wave] = bi; }
    __syncthreads();
    if (t == 0) {
        double tot = ((s_ws[0] + s_ws[1]) + (s_ws[2] + s_ws[3]));  // fixed order
        atomicAdd(&sumSim[(size_t)(iter & 1)*BB + b], tot);
        double cv = s_wv[0]; int ci = s_wi[0];
        #pragma unroll
        for (int w = 1; w < 4; ++w) {        // ascending wave = ascending n
            if (s_wv[w] > cv || (s_wv[w] == cv && s_wi[w] < ci)) { cv = s_wv[w]; ci = s_wi[w]; }
        }
        bmaxv[(size_t)b*NBX + blockIdx.x] = cv;
        bmaxi[(size_t)b*NBX + blockIdx.x] = ci;
    }

    // deferred repr finalize for the PREVIOUS iteration (fixed-order chains)
    if (iter > 0 && blockIdx.x == 0) {
        const int slotPrev = (iter-1) & 1;
        double ss = sumSim[(size_t)slotPrev*BB + b];
        if (t < CC) {
            double c0 = 0.0, c1 = 0.0, c2 = 0.0, c3 = 0.0;
            for (int nb = 0; nb < NBB; nb += 4) {
                c0 += wpart[((size_t)(nb+0)*BB + b)*CC + t];
                c1 += wpart[((size_t)(nb+1)*BB + b)*CC + t];
                c2 += wpart[((size_t)(nb+2)*BB + b)*CC + t];
                c3 += wpart[((size_t)(nb+3)*BB + b)*CC + t];
            }
            double tot2 = ((c0 + c1) + (c2 + c3));
            out[(size_t)(iter-1)*BB*CC + (size_t)b*CC + t] = (float)(tot2 / ss);
        }
        __syncthreads();
        if (t == 0) sumSim[(size_t)slotPrev*BB + b] = 0.0;
    }
}

// Final repr (iter 15): wpart from the tail fused call, sumSim slot 15&1.
__global__ void final_repr_kernel(float* __restrict__ out,
                                  const double* __restrict__ sumSim,
                                  const double* __restrict__ wpart)
{
    const int b = blockIdx.x;
    const int t = threadIdx.x;
    double ss = sumSim[(size_t)((NBVEC-1) & 1)*BB + b];
    if (t < CC) {
        double c0 = 0.0, c1 = 0.0, c2 = 0.0, c3 = 0.0;
        for (int nb = 0; nb < NBB; nb += 4) {
            c0 += wpart[((size_t)(nb+0)*BB + b)*CC + t];
            c1 += wpart[((size_t)(nb+1)*BB + b)*CC + t];
            c2 += wpart[((size_t)(nb+2)*BB + b)*CC + t];
            c3 += wpart[((size_t)(nb+3)*BB + b)*CC + t];
        }
        double tot = ((c0 + c1) + (c2 + c3));
        out[(size_t)(NBVEC-1)*BB*CC + (size_t)b*CC + t] = (float)(tot / ss);
    }
}

extern "C" void kernel_launch(void* const* d_in, const int* in_sizes, int n_in,
                              void* d_out, int out_size, void* d_ws, size_t ws_size,
                              hipStream_t stream)
{
    const float* x = (const float*)d_in[0];
    // d_in[1] (prior) is provably unused: ind at i==0 is forced to N/2 and
    // score is overwritten with (1 - sim) at i==0, discarding the prior.
    // d_in[2] (nbVec) fixed at 16 by the problem shapes.
    float* out = (float*)d_out;

    char* ws = (char*)d_ws;
    double* score  = (double*)(ws);
    float*  d2part = (float*) (ws + 1048576);
    double* wpart  = (double*)(ws + 9437184);
    double* sumSim = (double*)(ws + 9699328);
    double* bmaxv  = (double*)(ws + 9699456);
    int*    bmaxi  = (int*)   (ws + 9703552);

    // d_out/d_ws are poisoned before every launch: zero what we accumulate into.
    float* out_selpos = out + (size_t)NBVEC*BB*CC + (size_t)NBVEC*BB*NN;
    hipMemsetAsync(out_selpos, 0, (size_t)BB*NN*sizeof(float), stream);
    hipMemsetAsync(sumSim, 0, 2*BB*sizeof(double), stream);

    for (int i = 0; i <= NBVEC; ++i) {
        // F(i): d2 for rv_i (skipped at i==16), wsum for sim_{i-1} (skipped at i==0)
        fused_kernel<<<dim3(NBB, CSPLIT, BB), 256, 0, stream>>>(
            x, out, bmaxv, bmaxi, d2part, wpart, i);
        if (i < NBVEC)
            finish_kernel<<<dim3(NBX, BB), 256, 0, stream>>>(
                out, score, d2part, sumSim, wpart, bmaxv, bmaxi, i);
    }
    final_repr_kernel<<<BB, 256, 0, stream>>>(out, sumSim, wpart);
}